// Round 8
// baseline (466.143 us; speedup 1.0000x reference)
//
#include <hip/hip_runtime.h>
#include <hip/hip_bf16.h>

typedef unsigned short u16;
typedef __attribute__((ext_vector_type(8))) short bf16x8;
typedef __attribute__((ext_vector_type(4))) float f32x4;

#define MFMA16(a, b, c) __builtin_amdgcn_mfma_f32_16x16x32_bf16(a, b, c, 0, 0, 0)

__device__ __forceinline__ u16 f2b(float f) {
  union { float f; unsigned u; } x; x.f = f;
  return (u16)((x.u + 0x7fffu + ((x.u >> 16) & 1u)) >> 16);
}

__device__ __forceinline__ void gload_lds16(const void* g, void* l) {
  __builtin_amdgcn_global_load_lds(
      (const __attribute__((address_space(1))) void*)g,
      (__attribute__((address_space(3))) void*)l, 16, 0, 0);
}

// stage 64 rows x 192 cols bf16 -> LDS, chunk XOR-swizzled by row&7 (proj A).
__device__ __forceinline__ void stage_64x192(const u16* __restrict__ src,
                                             int stride, u16* dst, int wave,
                                             int lane) {
#pragma unroll
  for (int it = 0; it < 6; ++it) {
    int id = (it * 4 + wave) * 64 + lane;
    int row = id / 24, ph = id - row * 24;
    int lch = (ph & 24) | ((ph ^ (row & 7)) & 7);
    gload_lds16(src + (size_t)row * stride + lch * 8,
                dst + (it * 4 + wave) * 512);
  }
}

// ---------------- weight fp32 -> bf16 MFMA-B-fragment order ----------------
// W is [N][K] row-major. Frag (ct, ks): 16 cols (n) x 32 k. lane l holds
// n = ct*16+(l&15), k = ks*32+(l>>4)*8 + i (i=0..7). dst frag-major.
__global__ __launch_bounds__(256) void pack_kernel(const float* __restrict__ W,
                                                   u16* __restrict__ F, int NT,
                                                   int KS, int K) {
  int f = blockIdx.x * 256 + threadIdx.x;
  if (f >= NT * KS * 64) return;
  int l = f & 63, rest = f >> 6;
  int ks = rest % KS, ct = rest / KS;
  int row = ct * 16 + (l & 15);
  int col = ks * 32 + (l >> 4) * 8;
  const float* s = W + (size_t)row * K + col;
  u16* d = F + (size_t)f * 8;
#pragma unroll
  for (int i = 0; i < 8; ++i) d[i] = f2b(s[i]);
}

// ---------------- fused LN1 + shift/window + QKV GEMM (B from L2 frags) ----
__global__ __launch_bounds__(256, 2) void qkv_fused(
    const float* __restrict__ x, const float* __restrict__ n1w,
    const float* __restrict__ n1b, const u16* __restrict__ wf,
    const float* __restrict__ qkvb_, u16* __restrict__ qb,
    u16* __restrict__ kb, u16* __restrict__ vb, int tok0) {
  __shared__ __align__(16) u16 sA[12288];
  int tid = threadIdx.x, wave = tid >> 6, lane = tid & 63;
  int g = lane >> 4, c = lane & 15, wr = wave * 16;
  int m0 = blockIdx.x * 64;
  // --- LN1: wave owns 16 rows; write sA swizzled ---
  {
    float vals[12][4];
    int srcrow[4];
#pragma unroll
    for (int reg = 0; reg < 4; ++reg) {
      int rg = tok0 + m0 + wr + 4 * g + reg;
      int win = rg / 49, n = rg - win * 49;
      int bb = win >> 6, wi = win & 63, wh = wi >> 3, ww = wi & 7;
      int rr = n / 7, cc = n - rr * 7;
      int hs = wh * 7 + rr + 3; if (hs >= 56) hs -= 56;
      int ws = ww * 7 + cc + 3; if (ws >= 56) ws -= 56;
      srcrow[reg] = bb * 3136 + hs * 56 + ws;
    }
#pragma unroll
    for (int nt = 0; nt < 12; ++nt)
#pragma unroll
      for (int reg = 0; reg < 4; ++reg)
        vals[nt][reg] = x[(size_t)srcrow[reg] * 192 + nt * 16 + c];
#pragma unroll
    for (int reg = 0; reg < 4; ++reg) {
      float s = 0.f;
#pragma unroll
      for (int nt = 0; nt < 12; ++nt) s += vals[nt][reg];
      s += __shfl_xor(s, 1, 64); s += __shfl_xor(s, 2, 64);
      s += __shfl_xor(s, 4, 64); s += __shfl_xor(s, 8, 64);
      float m = s * (1.f / 192.f), q = 0.f;
#pragma unroll
      for (int nt = 0; nt < 12; ++nt) { float d = vals[nt][reg] - m; q += d * d; }
      q += __shfl_xor(q, 1, 64); q += __shfl_xor(q, 2, 64);
      q += __shfl_xor(q, 4, 64); q += __shfl_xor(q, 8, 64);
      float rs = rsqrtf(q * (1.f / 192.f) + 1e-5f);
#pragma unroll
      for (int nt = 0; nt < 12; ++nt) vals[nt][reg] = (vals[nt][reg] - m) * rs;
    }
#pragma unroll
    for (int nt = 0; nt < 12; ++nt) {
      float wv = n1w[nt * 16 + c], bv = n1b[nt * 16 + c];
#pragma unroll
      for (int reg = 0; reg < 4; ++reg) {
        int r = wr + 4 * g + reg;
        int ch = nt * 2 + (c >> 3);
        int ph = (ch & 24) | ((ch ^ (r & 7)) & 7);
        sA[r * 192 + ph * 8 + (c & 7)] = f2b(vals[nt][reg] * wv + bv);
      }
    }
  }
  __syncthreads();
  // --- A-frags: wave (mw,nw) covers rows mw*32..+31, cols nw-half ---
  int mw = wave >> 1, nw = wave & 1;
  bf16x8 afr[2][6];
#pragma unroll
  for (int rt = 0; rt < 2; ++rt) {
    int ar = mw * 32 + rt * 16 + c;
#pragma unroll
    for (int ks = 0; ks < 6; ++ks) {
      int ch = ks * 4 + g;
      int ph = (ch & 24) | ((ch ^ (ar & 7)) & 7);
      afr[rt][ks] = *(const bf16x8*)(sA + ar * 192 + ph * 8);
    }
  }
  int win0 = tok0 / 49;
  for (int j = 0; j < 9; ++j) {
    f32x4 S[2][2] = {{{0,0,0,0},{0,0,0,0}},{{0,0,0,0},{0,0,0,0}}};
#pragma unroll
    for (int nt = 0; nt < 2; ++nt) {
      int ctg = j * 4 + nw * 2 + nt;
#pragma unroll
      for (int ks = 0; ks < 6; ++ks) {
        bf16x8 bf = *(const bf16x8*)(wf + ((size_t)(ctg * 6 + ks) * 64 + lane) * 8);
        S[0][nt] = MFMA16(afr[0][ks], bf, S[0][nt]);
        S[1][nt] = MFMA16(afr[1][ks], bf, S[1][nt]);
      }
    }
    int which = j / 3;  // 0=q 1=k 2=v
    u16* dst = which == 0 ? qb : (which == 1 ? kb : vb);
#pragma unroll
    for (int nt = 0; nt < 2; ++nt) {
      int jc = j * 64 + nw * 32 + nt * 16 + c;
      int jj = jc - which * 192;
      int hh = jj >> 5, d = jj & 31;
      float bv = qkvb_[jc];
#pragma unroll
      for (int rt = 0; rt < 2; ++rt)
#pragma unroll
        for (int reg = 0; reg < 4; ++reg) {
          int rg = tok0 + m0 + mw * 32 + rt * 16 + 4 * g + reg;
          int win = rg / 49, n = rg - win * 49;
          dst[((size_t)((win - win0) * 6 + hh) * 49 + n) * 32 + d] =
              f2b(S[rt][nt][reg] + bv);
        }
    }
  }
}

// ---------------- attention: one (window, head) per block (unchanged) ------
__global__ __launch_bounds__(256) void attn_kernel(
    const u16* __restrict__ qb, const u16* __restrict__ kb,
    const u16* __restrict__ vb, const float* __restrict__ rpb,
    const float* __restrict__ amask, u16* __restrict__ aout, int win0) {
  __shared__ __align__(16) u16 qs[64 * 32], ks[64 * 32], vst[32 * 64];
  __shared__ __align__(16) float S[64 * 68];
  __shared__ __align__(16) u16 P[64 * 64];
  int tid = threadIdx.x;
  int blk = blockIdx.x;
  int winl = blk / 6, head = blk - winl * 6;
  int wi = (win0 + winl) & 63;
  const size_t base = (size_t)(winl * 6 + head) * 49 * 32;
  {
    int row = tid >> 2, kcl = tid & 3;
    int phys = kcl ^ (row & 3);
    uint4 qv = make_uint4(0, 0, 0, 0), kv = qv, vv = qv;
    if (row < 49) {
      size_t o = base + (size_t)row * 32 + kcl * 8;
      qv = *(const uint4*)(qb + o);
      kv = *(const uint4*)(kb + o);
      vv = *(const uint4*)(vb + o);
    }
    *(uint4*)(qs + row * 32 + phys * 8) = qv;
    *(uint4*)(ks + row * 32 + phys * 8) = kv;
    alignas(16) u16 vu[8];
    *(uint4*)vu = vv;
    int c8 = kcl * 8;
    int kc = row >> 3;
#pragma unroll
    for (int j = 0; j < 8; ++j) {
      int d = c8 + j;
      vst[d * 64 + ((kc ^ (d & 7)) * 8) + (row & 7)] = vu[j];
    }
  }
  __syncthreads();
  int wave = tid >> 6, lane = tid & 63;
  int col = lane & 15, g = lane >> 4;
  {
    int ar = wave * 16 + col;
    bf16x8 af = *(const bf16x8*)(qs + ar * 32 + ((g ^ (ar & 3)) * 8));
    f32x4 zero = {0.f, 0.f, 0.f, 0.f};
#pragma unroll
    for (int nt = 0; nt < 4; ++nt) {
      int br = nt * 16 + col;
      bf16x8 bfr = *(const bf16x8*)(ks + br * 32 + ((g ^ (br & 3)) * 8));
      f32x4 sacc = MFMA16(af, bfr, zero);
#pragma unroll
      for (int reg = 0; reg < 4; ++reg)
        S[(wave * 16 + 4 * g + reg) * 68 + nt * 16 + col] = sacc[reg];
    }
  }
  __syncthreads();
  {
    int r = tid >> 2, p = tid & 3;
    int rb = (r < 49) ? r : 0;
    int i1 = rb / 7, j1 = rb - i1 * 7;
    const float scale = 0.17677669529663687f;
    const float* Srow = S + r * 68;
    float vals[16];
    float mx = -1e30f;
#pragma unroll
    for (int t = 0; t < 16; ++t) {
      int cc = p * 16 + t;
      float v = -1e30f;
      if (cc < 49) {
        int i2 = cc / 7, j2 = cc - i2 * 7;
        int ridx = (i1 - i2 + 6) * 13 + (j1 - j2 + 6);
        v = Srow[cc] * scale + rpb[ridx * 6 + head] +
            amask[(size_t)wi * 2401 + rb * 49 + cc];
      }
      vals[t] = v;
      mx = fmaxf(mx, v);
    }
    mx = fmaxf(mx, __shfl_xor(mx, 1, 64));
    mx = fmaxf(mx, __shfl_xor(mx, 2, 64));
    float se = 0.f;
#pragma unroll
    for (int t = 0; t < 16; ++t) {
      float e = __expf(vals[t] - mx);
      vals[t] = e;
      se += e;
    }
    se += __shfl_xor(se, 1, 64);
    se += __shfl_xor(se, 2, 64);
    float inv = 1.0f / se;
#pragma unroll
    for (int t = 0; t < 16; ++t) {
      int cc = p * 16 + t;
      P[r * 64 + (((cc >> 3) ^ (r & 7)) * 8) + (cc & 7)] = f2b(vals[t] * inv);
    }
  }
  __syncthreads();
  {
    f32x4 oacc[2] = {{0,0,0,0},{0,0,0,0}};
    int ar = wave * 16 + col;
#pragma unroll
    for (int kt = 0; kt < 2; ++kt) {
      bf16x8 pf = *(const bf16x8*)(P + ar * 64 + (((kt * 4 + g) ^ (ar & 7)) * 8));
#pragma unroll
      for (int nt = 0; nt < 2; ++nt) {
        int d = nt * 16 + col;
        bf16x8 vf = *(const bf16x8*)(vst + d * 64 + (((kt * 4 + g) ^ (d & 7)) * 8));
        oacc[nt] = MFMA16(pf, vf, oacc[nt]);
      }
    }
#pragma unroll
    for (int nt = 0; nt < 2; ++nt)
#pragma unroll
      for (int reg = 0; reg < 4; ++reg) {
        int rloc = wave * 16 + 4 * g + reg;
        if (rloc < 49)
          aout[((size_t)winl * 49 + rloc) * 192 + head * 32 + nt * 16 + col] =
              f2b(oacc[nt][reg]);
      }
  }
}

// ---------------- fused proj + window reverse + unshift + residual ---------
__global__ __launch_bounds__(256, 2) void proj_fused(
    const u16* __restrict__ aout, const u16* __restrict__ wf,
    const float* __restrict__ pb, const float* __restrict__ x,
    float* __restrict__ out, int tok0) {
  __shared__ __align__(16) u16 sA[12288];
  int tid = threadIdx.x, wave = tid >> 6, lane = tid & 63;
  int g = lane >> 4, c = lane & 15;
  int m0 = blockIdx.x * 64;
  stage_64x192(aout + (size_t)m0 * 192, 192, sA, wave, lane);
  asm volatile("s_waitcnt vmcnt(0)" ::: "memory");
  __syncthreads();
  int mw = wave >> 1, nw = wave & 1;
  bf16x8 afr[2][6];
#pragma unroll
  for (int rt = 0; rt < 2; ++rt) {
    int ar = mw * 32 + rt * 16 + c;
#pragma unroll
    for (int ks = 0; ks < 6; ++ks) {
      int ch = ks * 4 + g;
      int ph = (ch & 24) | ((ch ^ (ar & 7)) & 7);
      afr[rt][ks] = *(const bf16x8*)(sA + ar * 192 + ph * 8);
    }
  }
  size_t trow[2][4];
#pragma unroll
  for (int rt = 0; rt < 2; ++rt)
#pragma unroll
    for (int reg = 0; reg < 4; ++reg) {
      int rg = tok0 + m0 + mw * 32 + rt * 16 + 4 * g + reg;
      int win = rg / 49, n = rg - win * 49;
      int b_ = win >> 6, wi = win & 63;
      int wh = wi >> 3, ww = wi & 7;
      int rr = n / 7, cc = n - rr * 7;
      int hd_ = wh * 7 + rr + 3; if (hd_ >= 56) hd_ -= 56;
      int wd = ww * 7 + cc + 3; if (wd >= 56) wd -= 56;
      trow[rt][reg] = (size_t)b_ * 3136 + hd_ * 56 + wd;
    }
  for (int j = 0; j < 3; ++j) {
    f32x4 S[2][2] = {{{0,0,0,0},{0,0,0,0}},{{0,0,0,0},{0,0,0,0}}};
#pragma unroll
    for (int nt = 0; nt < 2; ++nt) {
      int ctg = j * 4 + nw * 2 + nt;
#pragma unroll
      for (int ks = 0; ks < 6; ++ks) {
        bf16x8 bf = *(const bf16x8*)(wf + ((size_t)(ctg * 6 + ks) * 64 + lane) * 8);
        S[0][nt] = MFMA16(afr[0][ks], bf, S[0][nt]);
        S[1][nt] = MFMA16(afr[1][ks], bf, S[1][nt]);
      }
    }
#pragma unroll
    for (int nt = 0; nt < 2; ++nt) {
      int jc = j * 64 + nw * 32 + nt * 16 + c;
      float bv = pb[jc];
#pragma unroll
      for (int rt = 0; rt < 2; ++rt)
#pragma unroll
        for (int reg = 0; reg < 4; ++reg) {
          size_t o = trow[rt][reg] * 192 + jc;
          out[o] = x[o] + S[rt][nt][reg] + bv;
        }
    }
  }
}

// ---------------- fused LN2 + fc1 + GELU + fc2 + residual ------------------
// Weights as L2-resident frag-packed arrays; LDS only for A-tile and P-tile.
__global__ __launch_bounds__(256, 2) void mlp_fused(
    const float* __restrict__ n2w, const float* __restrict__ n2b,
    const u16* __restrict__ w1f, const float* __restrict__ b1,
    const u16* __restrict__ w2f, const float* __restrict__ b2,
    float* __restrict__ out) {
  __shared__ __align__(16) u16 sA[12288];  // 64x192
  __shared__ __align__(16) u16 sP[4096];   // 64x64
  int tid = threadIdx.x, wave = tid >> 6, lane = tid & 63;
  int g = lane >> 4, c = lane & 15, wr = wave * 16;
  int m0 = blockIdx.x * 64;
  // --- LN2: wave owns 16 rows -> sA swizzled ---
  {
    float v[12][4];
    int rr[4];
#pragma unroll
    for (int reg = 0; reg < 4; ++reg) rr[reg] = m0 + wr + 4 * g + reg;
#pragma unroll
    for (int nt = 0; nt < 12; ++nt)
#pragma unroll
      for (int reg = 0; reg < 4; ++reg)
        v[nt][reg] = out[(size_t)rr[reg] * 192 + nt * 16 + c];
#pragma unroll
    for (int reg = 0; reg < 4; ++reg) {
      float s = 0.f;
#pragma unroll
      for (int nt = 0; nt < 12; ++nt) s += v[nt][reg];
      s += __shfl_xor(s, 1, 64); s += __shfl_xor(s, 2, 64);
      s += __shfl_xor(s, 4, 64); s += __shfl_xor(s, 8, 64);
      float m = s * (1.f / 192.f), q = 0.f;
#pragma unroll
      for (int nt = 0; nt < 12; ++nt) { float d = v[nt][reg] - m; q += d * d; }
      q += __shfl_xor(q, 1, 64); q += __shfl_xor(q, 2, 64);
      q += __shfl_xor(q, 4, 64); q += __shfl_xor(q, 8, 64);
      float rs = rsqrtf(q * (1.f / 192.f) + 1e-5f);
#pragma unroll
      for (int nt = 0; nt < 12; ++nt) v[nt][reg] = (v[nt][reg] - m) * rs;
    }
#pragma unroll
    for (int nt = 0; nt < 12; ++nt) {
      float wv = n2w[nt * 16 + c], bv = n2b[nt * 16 + c];
#pragma unroll
      for (int reg = 0; reg < 4; ++reg) {
        int r = wr + 4 * g + reg;
        int ch = nt * 2 + (c >> 3);
        int ph = (ch & 24) | ((ch ^ (r & 7)) & 7);
        sA[r * 192 + ph * 8 + (c & 7)] = f2b(v[nt][reg] * wv + bv);
      }
    }
  }
  __syncthreads();
  int mw = wave >> 1, nw = wave & 1;
  bf16x8 afr[2][6];
#pragma unroll
  for (int rt = 0; rt < 2; ++rt) {
    int ar = mw * 32 + rt * 16 + c;
#pragma unroll
    for (int ks = 0; ks < 6; ++ks) {
      int ch = ks * 4 + g;
      int ph = (ch & 24) | ((ch ^ (ar & 7)) & 7);
      afr[rt][ks] = *(const bf16x8*)(sA + ar * 192 + ph * 8);
    }
  }
  f32x4 o[2][6];
#pragma unroll
  for (int rt = 0; rt < 2; ++rt)
#pragma unroll
    for (int ct = 0; ct < 6; ++ct) o[rt][ct] = (f32x4){0.f, 0.f, 0.f, 0.f};
  for (int j = 0; j < 12; ++j) {
    // ---- fc1: S = A @ w1_chunk^T (B-frags from L2) ----
    f32x4 S[2][2] = {{{0,0,0,0},{0,0,0,0}},{{0,0,0,0},{0,0,0,0}}};
#pragma unroll
    for (int nt = 0; nt < 2; ++nt) {
      int ctg = j * 4 + nw * 2 + nt;
#pragma unroll
      for (int ks = 0; ks < 6; ++ks) {
        bf16x8 bf = *(const bf16x8*)(w1f + ((size_t)(ctg * 6 + ks) * 64 + lane) * 8);
        S[0][nt] = MFMA16(afr[0][ks], bf, S[0][nt]);
        S[1][nt] = MFMA16(afr[1][ks], bf, S[1][nt]);
      }
    }
    // ---- fast GELU -> sP [64 m][64 h] swizzled (8 chunks/row) ----
#pragma unroll
    for (int nt = 0; nt < 2; ++nt) {
      float bv = b1[(j * 4 + nw * 2 + nt) * 16 + c];
      int col = nw * 32 + nt * 16 + c;
#pragma unroll
      for (int rt = 0; rt < 2; ++rt)
#pragma unroll
        for (int reg = 0; reg < 4; ++reg) {
          int r = mw * 32 + rt * 16 + 4 * g + reg;
          float vv = S[rt][nt][reg] + bv;
          float u2 = vv * (1.5957691216f + 0.0713548163f * vv * vv);
          float gl = vv / (1.f + __expf(-u2));
          int ph = (col >> 3) ^ (r & 7);
          sP[r * 64 + ph * 8 + (col & 7)] = f2b(gl);
        }
    }
    __syncthreads();  // sP visible (cross-nw handoff)
    // ---- PV: o += P @ w2_slice (B-frags from L2) ----
#pragma unroll
    for (int ks2 = 0; ks2 < 2; ++ks2) {
      bf16x8 pf[2];
#pragma unroll
      for (int rt = 0; rt < 2; ++rt) {
        int pr = mw * 32 + rt * 16 + c;
        int ch = ks2 * 4 + g;
        int ph = ch ^ (pr & 7);
        pf[rt] = *(const bf16x8*)(sP + pr * 64 + ph * 8);
      }
#pragma unroll
      for (int ct = 0; ct < 6; ++ct) {
        int ctg2 = nw * 6 + ct;
        bf16x8 bf = *(const bf16x8*)(
            w2f + ((size_t)(ctg2 * 24 + j * 2 + ks2) * 64 + lane) * 8);
        o[0][ct] = MFMA16(pf[0], bf, o[0][ct]);
        o[1][ct] = MFMA16(pf[1], bf, o[1][ct]);
      }
    }
    __syncthreads();  // sP reads done before next phase overwrites
  }
  // epilogue: residual (re-read) + bias
#pragma unroll
  for (int ct = 0; ct < 6; ++ct) {
    int col = nw * 96 + ct * 16 + c;
    float bv = b2[col];
#pragma unroll
    for (int rt = 0; rt < 2; ++rt)
#pragma unroll
      for (int reg = 0; reg < 4; ++reg) {
        size_t oo = (size_t)(m0 + mw * 32 + rt * 16 + 4 * g + reg) * 192 + col;
        out[oo] = out[oo] + o[rt][ct][reg] + bv;
      }
  }
}

extern "C" void kernel_launch(void* const* d_in, const int* in_sizes, int n_in,
                              void* d_out, int out_size, void* d_ws, size_t ws_size,
                              hipStream_t stream) {
  (void)in_sizes; (void)n_in; (void)out_size;
  const float* x     = (const float*)d_in[0];
  const float* amask = (const float*)d_in[1];
  const float* n1w   = (const float*)d_in[2];
  const float* n1b   = (const float*)d_in[3];
  const float* qkvw  = (const float*)d_in[4];
  const float* qkvb  = (const float*)d_in[5];
  const float* rpb   = (const float*)d_in[6];
  const float* projw = (const float*)d_in[7];
  const float* projb = (const float*)d_in[8];
  const float* n2w   = (const float*)d_in[9];
  const float* n2b   = (const float*)d_in[10];
  const float* fc1w  = (const float*)d_in[11];
  const float* fc1b  = (const float*)d_in[12];
  const float* fc2w  = (const float*)d_in[13];
  const float* fc2b  = (const float*)d_in[14];
  float* out = (float*)d_out;
  char* ws = (char*)d_ws;

  u16* qkvwf = (u16*)(ws);                               // 36x6 frags
  u16* projwf = (u16*)(ws + 221184);                     // 12x6
  u16* fc1wf = (u16*)(ws + 221184 + 73728);              // 48x6
  u16* fc2wf = (u16*)(ws + 221184 + 73728 + 294912);     // 12x24
  char* arena = ws + (1 << 20);
  size_t arena_sz = ws_size > (1 << 20) ? ws_size - (1 << 20) : 0;

  pack_kernel<<<(36 * 6 * 64 + 255) / 256, 256, 0, stream>>>(qkvw, qkvwf, 36, 6, 192);
  pack_kernel<<<(12 * 6 * 64 + 255) / 256, 256, 0, stream>>>(projw, projwf, 12, 6, 192);
  pack_kernel<<<(48 * 6 * 64 + 255) / 256, 256, 0, stream>>>(fc1w, fc1wf, 48, 6, 192);
  pack_kernel<<<(12 * 24 * 64 + 255) / 256, 256, 0, stream>>>(fc2w, fc2wf, 12, 24, 768);

  // ---- attention path, chunked over window groups (ws-size adaptive) ----
  int NCA = 1;
  while (NCA < 16 && 4ull * (size_t)(2048 / NCA) * 49 * 192 * 2 > arena_sz)
    NCA <<= 1;
  int Wc = 2048 / NCA;
  size_t Sx = (size_t)Wc * 49 * 192;  // u16 elements per buffer
  for (int cch = 0; cch < NCA; ++cch) {
    int win0 = cch * Wc;
    int tok0 = win0 * 49;
    u16* aout_c = (u16*)arena;
    u16* qb = (u16*)arena + Sx;
    u16* kb = qb + Sx;
    u16* vb = kb + Sx;
    int rows = Wc * 49;
    qkv_fused<<<rows / 64, 256, 0, stream>>>(x, n1w, n1b, qkvwf, qkvb,
                                             qb, kb, vb, tok0);
    attn_kernel<<<Wc * 6, 256, 0, stream>>>(qb, kb, vb, rpb, amask, aout_c,
                                            win0);
    proj_fused<<<rows / 64, 256, 0, stream>>>(aout_c, projwf, projb, x, out,
                                              tok0);
  }

  // ---- fused MLP: frag-packed weights from L2, minimal LDS ----
  mlp_fused<<<1568, 256, 0, stream>>>(n2w, n2b, fc1wf, fc1b, fc2wf, fc2b,
                                      out);
}

// Round 9
// 373.981 us; speedup vs baseline: 1.2464x; 1.2464x over previous
//
#include <hip/hip_runtime.h>
#include <hip/hip_bf16.h>

typedef unsigned short u16;
typedef __attribute__((ext_vector_type(8))) short bf16x8;
typedef __attribute__((ext_vector_type(4))) float f32x4;

#define MFMA16(a, b, c) __builtin_amdgcn_mfma_f32_16x16x32_bf16(a, b, c, 0, 0, 0)

__device__ __forceinline__ u16 f2b(float f) {
  union { float f; unsigned u; } x; x.f = f;
  return (u16)((x.u + 0x7fffu + ((x.u >> 16) & 1u)) >> 16);
}

__device__ __forceinline__ void gload_lds16(const void* g, void* l) {
  __builtin_amdgcn_global_load_lds(
      (const __attribute__((address_space(1))) void*)g,
      (__attribute__((address_space(3))) void*)l, 16, 0, 0);
}

// linear frag-block stage: NCH chunks of 512 u16 (64 lanes x 16B), src contiguous
template <int NCH>
__device__ __forceinline__ void stage_frags(const u16* __restrict__ src,
                                            u16* dst, int wave, int lane) {
#pragma unroll
  for (int it = 0; it < NCH / 4; ++it) {
    int chunk = it * 4 + wave;
    gload_lds16(src + ((size_t)chunk * 64 + lane) * 8, dst + chunk * 512);
  }
}

// stage 64 rows x 192 cols bf16 -> LDS, chunk XOR-swizzled by row&7 (proj A).
__device__ __forceinline__ void stage_64x192(const u16* __restrict__ src,
                                             int stride, u16* dst, int wave,
                                             int lane) {
#pragma unroll
  for (int it = 0; it < 6; ++it) {
    int id = (it * 4 + wave) * 64 + lane;
    int row = id / 24, ph = id - row * 24;
    int lch = (ph & 24) | ((ph ^ (row & 7)) & 7);
    gload_lds16(src + (size_t)row * stride + lch * 8,
                dst + (it * 4 + wave) * 512);
  }
}

// ---------------- weight fp32 -> bf16 MFMA-B-fragment order ----------------
// W is [N][K] row-major. Frag (ct,ks): lane l holds n=ct*16+(l&15),
// k=ks*32+(l>>4)*8+i. kmajor=0: frag id = ct*KS+ks; kmajor=1: id = ks*NT+ct.
__global__ __launch_bounds__(256) void pack_kernel(const float* __restrict__ W,
                                                   u16* __restrict__ F, int NT,
                                                   int KS, int K, int kmajor) {
  int f = blockIdx.x * 256 + threadIdx.x;
  if (f >= NT * KS * 64) return;
  int l = f & 63, rest = f >> 6;
  int ks, ct;
  if (kmajor) { ct = rest % NT; ks = rest / NT; }
  else        { ks = rest % KS; ct = rest / KS; }
  int row = ct * 16 + (l & 15);
  int col = ks * 32 + (l >> 4) * 8;
  const float* s = W + (size_t)row * K + col;
  u16* d = F + (size_t)f * 8;
#pragma unroll
  for (int i = 0; i < 8; ++i) d[i] = f2b(s[i]);
}

// ---------------- fused LN1 + shift/window + QKV GEMM ----------------------
__global__ __launch_bounds__(256, 3) void qkv_fused(
    const float* __restrict__ x, const float* __restrict__ n1w,
    const float* __restrict__ n1b, const u16* __restrict__ wf,
    const float* __restrict__ qkvb_, u16* __restrict__ qb,
    u16* __restrict__ kb, u16* __restrict__ vb, int tok0) {
  __shared__ __align__(16) u16 lds[24576];  // 48 KB
  u16* sA = lds;            // 12288 u16, overlays b0
  u16* b0 = lds;            // 24 frags (12288 u16)
  u16* b1 = lds + 12288;
  int tid = threadIdx.x, wave = tid >> 6, lane = tid & 63;
  int g = lane >> 4, c = lane & 15, wr = wave * 16;
  int m0 = blockIdx.x * 64;
  // --- LN1: wave owns 16 rows; write sA swizzled ---
  {
    float vals[12][4];
    int srcrow[4];
#pragma unroll
    for (int reg = 0; reg < 4; ++reg) {
      int rg = tok0 + m0 + wr + 4 * g + reg;
      int win = rg / 49, n = rg - win * 49;
      int bb = win >> 6, wi = win & 63, wh = wi >> 3, ww = wi & 7;
      int rr = n / 7, cc = n - rr * 7;
      int hs = wh * 7 + rr + 3; if (hs >= 56) hs -= 56;
      int ws = ww * 7 + cc + 3; if (ws >= 56) ws -= 56;
      srcrow[reg] = bb * 3136 + hs * 56 + ws;
    }
#pragma unroll
    for (int nt = 0; nt < 12; ++nt)
#pragma unroll
      for (int reg = 0; reg < 4; ++reg)
        vals[nt][reg] = x[(size_t)srcrow[reg] * 192 + nt * 16 + c];
#pragma unroll
    for (int reg = 0; reg < 4; ++reg) {
      float s = 0.f;
#pragma unroll
      for (int nt = 0; nt < 12; ++nt) s += vals[nt][reg];
      s += __shfl_xor(s, 1, 64); s += __shfl_xor(s, 2, 64);
      s += __shfl_xor(s, 4, 64); s += __shfl_xor(s, 8, 64);
      float m = s * (1.f / 192.f), q = 0.f;
#pragma unroll
      for (int nt = 0; nt < 12; ++nt) { float d = vals[nt][reg] - m; q += d * d; }
      q += __shfl_xor(q, 1, 64); q += __shfl_xor(q, 2, 64);
      q += __shfl_xor(q, 4, 64); q += __shfl_xor(q, 8, 64);
      float rs = rsqrtf(q * (1.f / 192.f) + 1e-5f);
#pragma unroll
      for (int nt = 0; nt < 12; ++nt) vals[nt][reg] = (vals[nt][reg] - m) * rs;
    }
#pragma unroll
    for (int nt = 0; nt < 12; ++nt) {
      float wv = n1w[nt * 16 + c], bv = n1b[nt * 16 + c];
#pragma unroll
      for (int reg = 0; reg < 4; ++reg) {
        int r = wr + 4 * g + reg;
        int ch = nt * 2 + (c >> 3);
        int ph = (ch & 24) | ((ch ^ (r & 7)) & 7);
        sA[r * 192 + ph * 8 + (c & 7)] = f2b(vals[nt][reg] * wv + bv);
      }
    }
  }
  __syncthreads();
  int mw = wave >> 1, nw = wave & 1;
  bf16x8 afr[2][6];
#pragma unroll
  for (int rt = 0; rt < 2; ++rt) {
    int ar = mw * 32 + rt * 16 + c;
#pragma unroll
    for (int ks = 0; ks < 6; ++ks) {
      int ch = ks * 4 + g;
      int ph = (ch & 24) | ((ch ^ (ar & 7)) & 7);
      afr[rt][ks] = *(const bf16x8*)(sA + ar * 192 + ph * 8);
    }
  }
  __syncthreads();  // sA dead -> b0 region reusable
  stage_frags<24>(wf, b0, wave, lane);
  int win0 = tok0 / 49;
  __syncthreads();  // b0 staged (barrier drains vmcnt)
  for (int j = 0; j < 9; ++j) {
    const u16* cb = (j & 1) ? b1 : b0;
    if (j < 8)
      stage_frags<24>(wf + (size_t)(j + 1) * 24 * 512, (j & 1) ? b0 : b1, wave,
                      lane);
    f32x4 S[2][2] = {{{0,0,0,0},{0,0,0,0}},{{0,0,0,0},{0,0,0,0}}};
#pragma unroll
    for (int nt = 0; nt < 2; ++nt)
#pragma unroll
      for (int ks = 0; ks < 6; ++ks) {
        bf16x8 bf = *(const bf16x8*)(cb + ((nw * 2 + nt) * 6 + ks) * 512 + lane * 8);
        S[0][nt] = MFMA16(afr[0][ks], bf, S[0][nt]);
        S[1][nt] = MFMA16(afr[1][ks], bf, S[1][nt]);
      }
    int which = j / 3;  // 0=q 1=k 2=v
    u16* dst = which == 0 ? qb : (which == 1 ? kb : vb);
#pragma unroll
    for (int nt = 0; nt < 2; ++nt) {
      int jc = j * 64 + nw * 32 + nt * 16 + c;
      int jj = jc - which * 192;
      int hh = jj >> 5, d = jj & 31;
      float bv = qkvb_[jc];
#pragma unroll
      for (int rt = 0; rt < 2; ++rt)
#pragma unroll
        for (int reg = 0; reg < 4; ++reg) {
          int rg = tok0 + m0 + mw * 32 + rt * 16 + 4 * g + reg;
          int win = rg / 49, n = rg - win * 49;
          dst[((size_t)((win - win0) * 6 + hh) * 49 + n) * 32 + d] =
              f2b(S[rt][nt][reg] + bv);
        }
    }
    __syncthreads();  // stage(j+1) drained; cb reads done
  }
}

// ---------------- attention: one (window, head) per block (unchanged) ------
__global__ __launch_bounds__(256) void attn_kernel(
    const u16* __restrict__ qb, const u16* __restrict__ kb,
    const u16* __restrict__ vb, const float* __restrict__ rpb,
    const float* __restrict__ amask, u16* __restrict__ aout, int win0) {
  __shared__ __align__(16) u16 qs[64 * 32], ks[64 * 32], vst[32 * 64];
  __shared__ __align__(16) float S[64 * 68];
  __shared__ __align__(16) u16 P[64 * 64];
  int tid = threadIdx.x;
  int blk = blockIdx.x;
  int winl = blk / 6, head = blk - winl * 6;
  int wi = (win0 + winl) & 63;
  const size_t base = (size_t)(winl * 6 + head) * 49 * 32;
  {
    int row = tid >> 2, kcl = tid & 3;
    int phys = kcl ^ (row & 3);
    uint4 qv = make_uint4(0, 0, 0, 0), kv = qv, vv = qv;
    if (row < 49) {
      size_t o = base + (size_t)row * 32 + kcl * 8;
      qv = *(const uint4*)(qb + o);
      kv = *(const uint4*)(kb + o);
      vv = *(const uint4*)(vb + o);
    }
    *(uint4*)(qs + row * 32 + phys * 8) = qv;
    *(uint4*)(ks + row * 32 + phys * 8) = kv;
    alignas(16) u16 vu[8];
    *(uint4*)vu = vv;
    int c8 = kcl * 8;
    int kc = row >> 3;
#pragma unroll
    for (int j = 0; j < 8; ++j) {
      int d = c8 + j;
      vst[d * 64 + ((kc ^ (d & 7)) * 8) + (row & 7)] = vu[j];
    }
  }
  __syncthreads();
  int wave = tid >> 6, lane = tid & 63;
  int col = lane & 15, g = lane >> 4;
  {
    int ar = wave * 16 + col;
    bf16x8 af = *(const bf16x8*)(qs + ar * 32 + ((g ^ (ar & 3)) * 8));
    f32x4 zero = {0.f, 0.f, 0.f, 0.f};
#pragma unroll
    for (int nt = 0; nt < 4; ++nt) {
      int br = nt * 16 + col;
      bf16x8 bfr = *(const bf16x8*)(ks + br * 32 + ((g ^ (br & 3)) * 8));
      f32x4 sacc = MFMA16(af, bfr, zero);
#pragma unroll
      for (int reg = 0; reg < 4; ++reg)
        S[(wave * 16 + 4 * g + reg) * 68 + nt * 16 + col] = sacc[reg];
    }
  }
  __syncthreads();
  {
    int r = tid >> 2, p = tid & 3;
    int rb = (r < 49) ? r : 0;
    int i1 = rb / 7, j1 = rb - i1 * 7;
    const float scale = 0.17677669529663687f;
    const float* Srow = S + r * 68;
    float vals[16];
    float mx = -1e30f;
#pragma unroll
    for (int t = 0; t < 16; ++t) {
      int cc = p * 16 + t;
      float v = -1e30f;
      if (cc < 49) {
        int i2 = cc / 7, j2 = cc - i2 * 7;
        int ridx = (i1 - i2 + 6) * 13 + (j1 - j2 + 6);
        v = Srow[cc] * scale + rpb[ridx * 6 + head] +
            amask[(size_t)wi * 2401 + rb * 49 + cc];
      }
      vals[t] = v;
      mx = fmaxf(mx, v);
    }
    mx = fmaxf(mx, __shfl_xor(mx, 1, 64));
    mx = fmaxf(mx, __shfl_xor(mx, 2, 64));
    float se = 0.f;
#pragma unroll
    for (int t = 0; t < 16; ++t) {
      float e = __expf(vals[t] - mx);
      vals[t] = e;
      se += e;
    }
    se += __shfl_xor(se, 1, 64);
    se += __shfl_xor(se, 2, 64);
    float inv = 1.0f / se;
#pragma unroll
    for (int t = 0; t < 16; ++t) {
      int cc = p * 16 + t;
      P[r * 64 + (((cc >> 3) ^ (r & 7)) * 8) + (cc & 7)] = f2b(vals[t] * inv);
    }
  }
  __syncthreads();
  {
    f32x4 oacc[2] = {{0,0,0,0},{0,0,0,0}};
    int ar = wave * 16 + col;
#pragma unroll
    for (int kt = 0; kt < 2; ++kt) {
      bf16x8 pf = *(const bf16x8*)(P + ar * 64 + (((kt * 4 + g) ^ (ar & 7)) * 8));
#pragma unroll
      for (int nt = 0; nt < 2; ++nt) {
        int d = nt * 16 + col;
        bf16x8 vf = *(const bf16x8*)(vst + d * 64 + (((kt * 4 + g) ^ (d & 7)) * 8));
        oacc[nt] = MFMA16(pf, vf, oacc[nt]);
      }
    }
#pragma unroll
    for (int nt = 0; nt < 2; ++nt)
#pragma unroll
      for (int reg = 0; reg < 4; ++reg) {
        int rloc = wave * 16 + 4 * g + reg;
        if (rloc < 49)
          aout[((size_t)winl * 49 + rloc) * 192 + head * 32 + nt * 16 + col] =
              f2b(oacc[nt][reg]);
      }
  }
}

// ---------------- fused proj + window reverse + unshift + residual ---------
__global__ __launch_bounds__(256, 3) void proj_fused(
    const u16* __restrict__ aout, const u16* __restrict__ wf,
    const float* __restrict__ pb, const float* __restrict__ x,
    float* __restrict__ out, int tok0) {
  __shared__ __align__(16) u16 lds[24576];  // 48 KB
  u16* sA = lds;
  u16* b0 = lds;
  u16* b1 = lds + 12288;
  int tid = threadIdx.x, wave = tid >> 6, lane = tid & 63;
  int g = lane >> 4, c = lane & 15;
  int m0 = blockIdx.x * 64;
  stage_64x192(aout + (size_t)m0 * 192, 192, sA, wave, lane);
  asm volatile("s_waitcnt vmcnt(0)" ::: "memory");
  __syncthreads();
  int mw = wave >> 1, nw = wave & 1;
  bf16x8 afr[2][6];
#pragma unroll
  for (int rt = 0; rt < 2; ++rt) {
    int ar = mw * 32 + rt * 16 + c;
#pragma unroll
    for (int ks = 0; ks < 6; ++ks) {
      int ch = ks * 4 + g;
      int ph = (ch & 24) | ((ch ^ (ar & 7)) & 7);
      afr[rt][ks] = *(const bf16x8*)(sA + ar * 192 + ph * 8);
    }
  }
  size_t trow[2][4];
#pragma unroll
  for (int rt = 0; rt < 2; ++rt)
#pragma unroll
    for (int reg = 0; reg < 4; ++reg) {
      int rg = tok0 + m0 + mw * 32 + rt * 16 + 4 * g + reg;
      int win = rg / 49, n = rg - win * 49;
      int b_ = win >> 6, wi = win & 63;
      int wh = wi >> 3, ww = wi & 7;
      int rr = n / 7, cc = n - rr * 7;
      int hd_ = wh * 7 + rr + 3; if (hd_ >= 56) hd_ -= 56;
      int wd = ww * 7 + cc + 3; if (wd >= 56) wd -= 56;
      trow[rt][reg] = (size_t)b_ * 3136 + hd_ * 56 + wd;
    }
  __syncthreads();  // afr reads done -> sA region (b0) reusable
  stage_frags<24>(wf, b0, wave, lane);
  __syncthreads();  // b0 staged
  for (int j = 0; j < 3; ++j) {
    const u16* cb = (j & 1) ? b1 : b0;
    if (j < 2)
      stage_frags<24>(wf + (size_t)(j + 1) * 24 * 512, (j & 1) ? b0 : b1, wave,
                      lane);
    f32x4 S[2][2] = {{{0,0,0,0},{0,0,0,0}},{{0,0,0,0},{0,0,0,0}}};
#pragma unroll
    for (int nt = 0; nt < 2; ++nt)
#pragma unroll
      for (int ks = 0; ks < 6; ++ks) {
        bf16x8 bf = *(const bf16x8*)(cb + ((nw * 2 + nt) * 6 + ks) * 512 + lane * 8);
        S[0][nt] = MFMA16(afr[0][ks], bf, S[0][nt]);
        S[1][nt] = MFMA16(afr[1][ks], bf, S[1][nt]);
      }
#pragma unroll
    for (int nt = 0; nt < 2; ++nt) {
      int jc = j * 64 + nw * 32 + nt * 16 + c;
      float bv = pb[jc];
#pragma unroll
      for (int rt = 0; rt < 2; ++rt)
#pragma unroll
        for (int reg = 0; reg < 4; ++reg) {
          size_t o = trow[rt][reg] * 192 + jc;
          out[o] = x[o] + S[rt][nt][reg] + bv;
        }
    }
    __syncthreads();
  }
}

// ---------------- fused LN2 + fc1 + GELU + fc2 + residual ------------------
// Frag-packed weights staged linearly to LDS (dbuf); lane-contiguous reads.
__global__ __launch_bounds__(256, 3) void mlp_fused(
    const float* __restrict__ n2w, const float* __restrict__ n2b,
    const u16* __restrict__ w1f, const float* __restrict__ b1,
    const u16* __restrict__ w2f, const float* __restrict__ b2,
    float* __restrict__ out) {
  __shared__ __align__(16) u16 lds[27136];  // 54272 B -> 3 blocks/CU
  u16* sA  = lds;            // 64x192 (12288 u16), overlays c1a+c1b
  u16* c1a = lds;            // 12 frags (6144 u16)
  u16* c1b = lds + 6144;
  u16* c2a = lds + 12288;
  u16* c2b = lds + 18432;
  u16* sP  = lds + 24576;    // 64x40 u16 (padded, 16B-aligned rows)
  int tid = threadIdx.x, wave = tid >> 6, lane = tid & 63;
  int g = lane >> 4, c = lane & 15, wr = wave * 16;
  int m0 = blockIdx.x * 64;
  // --- LN2: wave owns 16 rows -> sA swizzled ---
  {
    float v[12][4];
    int rr[4];
#pragma unroll
    for (int reg = 0; reg < 4; ++reg) rr[reg] = m0 + wr + 4 * g + reg;
#pragma unroll
    for (int nt = 0; nt < 12; ++nt)
#pragma unroll
      for (int reg = 0; reg < 4; ++reg)
        v[nt][reg] = out[(size_t)rr[reg] * 192 + nt * 16 + c];
#pragma unroll
    for (int reg = 0; reg < 4; ++reg) {
      float s = 0.f;
#pragma unroll
      for (int nt = 0; nt < 12; ++nt) s += v[nt][reg];
      s += __shfl_xor(s, 1, 64); s += __shfl_xor(s, 2, 64);
      s += __shfl_xor(s, 4, 64); s += __shfl_xor(s, 8, 64);
      float m = s * (1.f / 192.f), q = 0.f;
#pragma unroll
      for (int nt = 0; nt < 12; ++nt) { float d = v[nt][reg] - m; q += d * d; }
      q += __shfl_xor(q, 1, 64); q += __shfl_xor(q, 2, 64);
      q += __shfl_xor(q, 4, 64); q += __shfl_xor(q, 8, 64);
      float rs = rsqrtf(q * (1.f / 192.f) + 1e-5f);
#pragma unroll
      for (int nt = 0; nt < 12; ++nt) v[nt][reg] = (v[nt][reg] - m) * rs;
    }
#pragma unroll
    for (int nt = 0; nt < 12; ++nt) {
      float wv = n2w[nt * 16 + c], bv = n2b[nt * 16 + c];
#pragma unroll
      for (int reg = 0; reg < 4; ++reg) {
        int r = wr + 4 * g + reg;
        int ch = nt * 2 + (c >> 3);
        int ph = (ch & 24) | ((ch ^ (r & 7)) & 7);
        sA[r * 192 + ph * 8 + (c & 7)] = f2b(v[nt][reg] * wv + bv);
      }
    }
  }
  __syncthreads();
  int mw = wave >> 1, nw = wave & 1;
  bf16x8 afr[2][6];
#pragma unroll
  for (int rt = 0; rt < 2; ++rt) {
    int ar = mw * 32 + rt * 16 + c;
#pragma unroll
    for (int ks = 0; ks < 6; ++ks) {
      int ch = ks * 4 + g;
      int ph = (ch & 24) | ((ch ^ (ar & 7)) & 7);
      afr[rt][ks] = *(const bf16x8*)(sA + ar * 192 + ph * 8);
    }
  }
  __syncthreads();  // sA dead -> c1a/c1b reusable
  stage_frags<12>(w1f, c1a, wave, lane);
  stage_frags<12>(w2f, c2a, wave, lane);
  f32x4 o[2][6];
#pragma unroll
  for (int rt = 0; rt < 2; ++rt)
#pragma unroll
    for (int ct = 0; ct < 6; ++ct) o[rt][ct] = (f32x4){0.f, 0.f, 0.f, 0.f};
  __syncthreads();  // prologue stage drained
  for (int j = 0; j < 24; ++j) {
    int cur = j & 1;
    const u16* r1 = cur ? c1b : c1a;
    const u16* r2 = cur ? c2b : c2a;
    if (j < 23)
      stage_frags<12>(w1f + (size_t)(j + 1) * 12 * 512, cur ? c1a : c1b, wave,
                      lane);
    // ---- fc1: one 16-col tile per wave (ct = 2j + nw) ----
    f32x4 S[2] = {{0,0,0,0},{0,0,0,0}};
#pragma unroll
    for (int ks = 0; ks < 6; ++ks) {
      bf16x8 bf = *(const bf16x8*)(r1 + (nw * 6 + ks) * 512 + lane * 8);
      S[0] = MFMA16(afr[0][ks], bf, S[0]);
      S[1] = MFMA16(afr[1][ks], bf, S[1]);
    }
    // ---- fast GELU -> sP (padded [64][40]) ----
    {
      float bv = b1[(j * 2 + nw) * 16 + c];
      int col = nw * 16 + c;
#pragma unroll
      for (int rt = 0; rt < 2; ++rt)
#pragma unroll
        for (int reg = 0; reg < 4; ++reg) {
          int r = mw * 32 + rt * 16 + 4 * g + reg;
          float vv = S[rt][reg] + bv;
          float u2 = vv * (1.5957691216f + 0.0713548163f * vv * vv);
          float gl = vv / (1.f + __expf(-u2));
          sP[r * 40 + col] = f2b(gl);
        }
    }
    __syncthreads();  // sP visible; fc1(j+1) stage drained
    if (j < 23)
      stage_frags<12>(w2f + (size_t)(j + 1) * 12 * 512, cur ? c2a : c2b, wave,
                      lane);
    // ---- PV: o += P @ w2_slice (6 n-tiles per wave) ----
    bf16x8 pf[2];
#pragma unroll
    for (int rt = 0; rt < 2; ++rt) {
      int pr = mw * 32 + rt * 16 + c;
      pf[rt] = *(const bf16x8*)(sP + pr * 40 + g * 8);
    }
#pragma unroll
    for (int ct = 0; ct < 6; ++ct) {
      bf16x8 bf = *(const bf16x8*)(r2 + (nw * 6 + ct) * 512 + lane * 8);
      o[0][ct] = MFMA16(pf[0], bf, o[0][ct]);
      o[1][ct] = MFMA16(pf[1], bf, o[1][ct]);
    }
    __syncthreads();  // sP reads done; fc2(j+1) stage drained
  }
  // epilogue: residual (re-read) + bias
#pragma unroll
  for (int ct = 0; ct < 6; ++ct) {
    int col = (nw * 6 + ct) * 16 + c;
    float bv = b2[col];
#pragma unroll
    for (int rt = 0; rt < 2; ++rt)
#pragma unroll
      for (int reg = 0; reg < 4; ++reg) {
        size_t oo = (size_t)(m0 + mw * 32 + rt * 16 + 4 * g + reg) * 192 + col;
        out[oo] = out[oo] + o[rt][ct][reg] + bv;
      }
  }
}

extern "C" void kernel_launch(void* const* d_in, const int* in_sizes, int n_in,
                              void* d_out, int out_size, void* d_ws, size_t ws_size,
                              hipStream_t stream) {
  (void)in_sizes; (void)n_in; (void)out_size;
  const float* x     = (const float*)d_in[0];
  const float* amask = (const float*)d_in[1];
  const float* n1w   = (const float*)d_in[2];
  const float* n1b   = (const float*)d_in[3];
  const float* qkvw  = (const float*)d_in[4];
  const float* qkvb  = (const float*)d_in[5];
  const float* rpb   = (const float*)d_in[6];
  const float* projw = (const float*)d_in[7];
  const float* projb = (const float*)d_in[8];
  const float* n2w   = (const float*)d_in[9];
  const float* n2b   = (const float*)d_in[10];
  const float* fc1w  = (const float*)d_in[11];
  const float* fc1b  = (const float*)d_in[12];
  const float* fc2w  = (const float*)d_in[13];
  const float* fc2b  = (const float*)d_in[14];
  float* out = (float*)d_out;
  char* ws = (char*)d_ws;

  u16* qkvwf = (u16*)(ws);                               // ct-major 36x6
  u16* projwf = (u16*)(ws + 221184);                     // ct-major 12x6
  u16* fc1wf = (u16*)(ws + 221184 + 73728);              // ct-major 48x6
  u16* fc2wf = (u16*)(ws + 221184 + 73728 + 294912);     // k-major 12x24
  char* arena = ws + (1 << 20);
  size_t arena_sz = ws_size > (1 << 20) ? ws_size - (1 << 20) : 0;

  pack_kernel<<<(36 * 6 * 64 + 255) / 256, 256, 0, stream>>>(qkvw, qkvwf, 36, 6, 192, 0);
  pack_kernel<<<(12 * 6 * 64 + 255) / 256, 256, 0, stream>>>(projw, projwf, 12, 6, 192, 0);
  pack_kernel<<<(48 * 6 * 64 + 255) / 256, 256, 0, stream>>>(fc1w, fc1wf, 48, 6, 192, 0);
  pack_kernel<<<(12 * 24 * 64 + 255) / 256, 256, 0, stream>>>(fc2w, fc2wf, 12, 24, 768, 1);

  // ---- attention path, chunked over window groups (ws-size adaptive) ----
  int NCA = 1;
  while (NCA < 16 && 4ull * (size_t)(2048 / NCA) * 49 * 192 * 2 > arena_sz)
    NCA <<= 1;
  int Wc = 2048 / NCA;
  size_t Sx = (size_t)Wc * 49 * 192;  // u16 elements per buffer
  for (int cch = 0; cch < NCA; ++cch) {
    int win0 = cch * Wc;
    int tok0 = win0 * 49;
    u16* aout_c = (u16*)arena;
    u16* qb = (u16*)arena + Sx;
    u16* kb = qb + Sx;
    u16* vb = kb + Sx;
    int rows = Wc * 49;
    qkv_fused<<<rows / 64, 256, 0, stream>>>(x, n1w, n1b, qkvwf, qkvb,
                                             qb, kb, vb, tok0);
    attn_kernel<<<Wc * 6, 256, 0, stream>>>(qb, kb, vb, rpb, amask, aout_c,
                                            win0);
    proj_fused<<<rows / 64, 256, 0, stream>>>(aout_c, projwf, projb, x, out,
                                              tok0);
  }

  // ---- fused MLP: frag-packed weights, LDS-staged, conflict-free ----
  mlp_fused<<<1568, 256, 0, stream>>>(n2w, n2b, fc1wf, fc1b, fc2wf, fc2b,
                                      out);
}

// Round 10
// 334.389 us; speedup vs baseline: 1.3940x; 1.1184x over previous
//
#include <hip/hip_runtime.h>
#include <hip/hip_bf16.h>

typedef unsigned short u16;
typedef __attribute__((ext_vector_type(8))) short bf16x8;
typedef __attribute__((ext_vector_type(4))) float f32x4;

#define MFMA16(a, b, c) __builtin_amdgcn_mfma_f32_16x16x32_bf16(a, b, c, 0, 0, 0)

__device__ __forceinline__ u16 f2b(float f) {
  union { float f; unsigned u; } x; x.f = f;
  return (u16)((x.u + 0x7fffu + ((x.u >> 16) & 1u)) >> 16);
}

__device__ __forceinline__ void gload_lds16(const void* g, void* l) {
  __builtin_amdgcn_global_load_lds(
      (const __attribute__((address_space(1))) void*)g,
      (__attribute__((address_space(3))) void*)l, 16, 0, 0);
}

// linear frag-block stage: NCH chunks of 512 u16 (64 lanes x 16B), src contiguous
template <int NCH>
__device__ __forceinline__ void stage_frags(const u16* __restrict__ src,
                                            u16* dst, int wave, int lane) {
#pragma unroll
  for (int it = 0; it < NCH / 4; ++it) {
    int chunk = it * 4 + wave;
    gload_lds16(src + ((size_t)chunk * 64 + lane) * 8, dst + chunk * 512);
  }
}

// stage 64 rows x 192 cols bf16 -> LDS, chunk XOR-swizzled by row&7 (proj A).
__device__ __forceinline__ void stage_64x192(const u16* __restrict__ src,
                                             int stride, u16* dst, int wave,
                                             int lane) {
#pragma unroll
  for (int it = 0; it < 6; ++it) {
    int id = (it * 4 + wave) * 64 + lane;
    int row = id / 24, ph = id - row * 24;
    int lch = (ph & 24) | ((ph ^ (row & 7)) & 7);
    gload_lds16(src + (size_t)row * stride + lch * 8,
                dst + (it * 4 + wave) * 512);
  }
}

// ---------------- weight fp32 -> bf16 MFMA-fragment order ------------------
// W is [N][K] row-major. Frag (ct,ks): lane l holds n=ct*16+(l&15),
// k=ks*32+(l>>4)*8+i. kmajor=0: frag id = ct*KS+ks; kmajor=1: id = ks*NT+ct.
__global__ __launch_bounds__(256) void pack_kernel(const float* __restrict__ W,
                                                   u16* __restrict__ F, int NT,
                                                   int KS, int K, int kmajor) {
  int f = blockIdx.x * 256 + threadIdx.x;
  if (f >= NT * KS * 64) return;
  int l = f & 63, rest = f >> 6;
  int ks, ct;
  if (kmajor) { ct = rest % NT; ks = rest / NT; }
  else        { ks = rest % KS; ct = rest / KS; }
  int row = ct * 16 + (l & 15);
  int col = ks * 32 + (l >> 4) * 8;
  const float* s = W + (size_t)row * K + col;
  u16* d = F + (size_t)f * 8;
#pragma unroll
  for (int i = 0; i < 8; ++i) d[i] = f2b(s[i]);
}

// fc2 pack with pi-permuted k within each 32-h chunk (matches lane-local pf):
// pi(g,i) = 4g+i (i<4), 16+4g+(i-4) (i>=4). frag id = hs*12 + ct.
__global__ __launch_bounds__(256) void pack2_kernel(const float* __restrict__ W,
                                                    u16* __restrict__ F) {
  int f = blockIdx.x * 256 + threadIdx.x;
  if (f >= 24 * 12 * 64) return;
  int l = f & 63, rest = f >> 6;
  int ct = rest % 12, hs = rest / 12;
  int row = ct * 16 + (l & 15);
  int g = l >> 4;
  u16* d = F + (size_t)f * 8;
#pragma unroll
  for (int i = 0; i < 8; ++i) {
    int h = hs * 32 + (i < 4 ? 4 * g + i : 16 + 4 * g + (i - 4));
    d[i] = f2b(W[(size_t)row * 768 + h]);
  }
}

// ---------------- fused LN1 + shift/window + QKV GEMM ----------------------
__global__ __launch_bounds__(256, 3) void qkv_fused(
    const float* __restrict__ x, const float* __restrict__ n1w,
    const float* __restrict__ n1b, const u16* __restrict__ wf,
    const float* __restrict__ qkvb_, u16* __restrict__ qb,
    u16* __restrict__ kb, u16* __restrict__ vb, int tok0) {
  __shared__ __align__(16) u16 lds[24576];  // 48 KB
  u16* sA = lds;            // 12288 u16, overlays b0
  u16* b0 = lds;            // 24 frags (12288 u16)
  u16* b1 = lds + 12288;
  int tid = threadIdx.x, wave = tid >> 6, lane = tid & 63;
  int g = lane >> 4, c = lane & 15, wr = wave * 16;
  int m0 = blockIdx.x * 64;
  // --- LN1: wave owns 16 rows; write sA swizzled ---
  {
    float vals[12][4];
    int srcrow[4];
#pragma unroll
    for (int reg = 0; reg < 4; ++reg) {
      int rg = tok0 + m0 + wr + 4 * g + reg;
      int win = rg / 49, n = rg - win * 49;
      int bb = win >> 6, wi = win & 63, wh = wi >> 3, ww = wi & 7;
      int rr = n / 7, cc = n - rr * 7;
      int hs = wh * 7 + rr + 3; if (hs >= 56) hs -= 56;
      int ws = ww * 7 + cc + 3; if (ws >= 56) ws -= 56;
      srcrow[reg] = bb * 3136 + hs * 56 + ws;
    }
#pragma unroll
    for (int nt = 0; nt < 12; ++nt)
#pragma unroll
      for (int reg = 0; reg < 4; ++reg)
        vals[nt][reg] = x[(size_t)srcrow[reg] * 192 + nt * 16 + c];
#pragma unroll
    for (int reg = 0; reg < 4; ++reg) {
      float s = 0.f;
#pragma unroll
      for (int nt = 0; nt < 12; ++nt) s += vals[nt][reg];
      s += __shfl_xor(s, 1, 64); s += __shfl_xor(s, 2, 64);
      s += __shfl_xor(s, 4, 64); s += __shfl_xor(s, 8, 64);
      float m = s * (1.f / 192.f), q = 0.f;
#pragma unroll
      for (int nt = 0; nt < 12; ++nt) { float d = vals[nt][reg] - m; q += d * d; }
      q += __shfl_xor(q, 1, 64); q += __shfl_xor(q, 2, 64);
      q += __shfl_xor(q, 4, 64); q += __shfl_xor(q, 8, 64);
      float rs = rsqrtf(q * (1.f / 192.f) + 1e-5f);
#pragma unroll
      for (int nt = 0; nt < 12; ++nt) vals[nt][reg] = (vals[nt][reg] - m) * rs;
    }
#pragma unroll
    for (int nt = 0; nt < 12; ++nt) {
      float wv = n1w[nt * 16 + c], bv = n1b[nt * 16 + c];
#pragma unroll
      for (int reg = 0; reg < 4; ++reg) {
        int r = wr + 4 * g + reg;
        int ch = nt * 2 + (c >> 3);
        int ph = (ch & 24) | ((ch ^ (r & 7)) & 7);
        sA[r * 192 + ph * 8 + (c & 7)] = f2b(vals[nt][reg] * wv + bv);
      }
    }
  }
  __syncthreads();
  int mw = wave >> 1, nw = wave & 1;
  bf16x8 afr[2][6];
#pragma unroll
  for (int rt = 0; rt < 2; ++rt) {
    int ar = mw * 32 + rt * 16 + c;
#pragma unroll
    for (int ks = 0; ks < 6; ++ks) {
      int ch = ks * 4 + g;
      int ph = (ch & 24) | ((ch ^ (ar & 7)) & 7);
      afr[rt][ks] = *(const bf16x8*)(sA + ar * 192 + ph * 8);
    }
  }
  __syncthreads();  // sA dead -> b0 region reusable
  stage_frags<24>(wf, b0, wave, lane);
  int win0 = tok0 / 49;
  __syncthreads();  // b0 staged (barrier drains vmcnt)
  for (int j = 0; j < 9; ++j) {
    const u16* cb = (j & 1) ? b1 : b0;
    if (j < 8)
      stage_frags<24>(wf + (size_t)(j + 1) * 24 * 512, (j & 1) ? b0 : b1, wave,
                      lane);
    f32x4 S[2][2] = {{{0,0,0,0},{0,0,0,0}},{{0,0,0,0},{0,0,0,0}}};
#pragma unroll
    for (int nt = 0; nt < 2; ++nt)
#pragma unroll
      for (int ks = 0; ks < 6; ++ks) {
        bf16x8 bf = *(const bf16x8*)(cb + ((nw * 2 + nt) * 6 + ks) * 512 + lane * 8);
        S[0][nt] = MFMA16(afr[0][ks], bf, S[0][nt]);
        S[1][nt] = MFMA16(afr[1][ks], bf, S[1][nt]);
      }
    int which = j / 3;  // 0=q 1=k 2=v
    u16* dst = which == 0 ? qb : (which == 1 ? kb : vb);
#pragma unroll
    for (int nt = 0; nt < 2; ++nt) {
      int jc = j * 64 + nw * 32 + nt * 16 + c;
      int jj = jc - which * 192;
      int hh = jj >> 5, d = jj & 31;
      float bv = qkvb_[jc];
#pragma unroll
      for (int rt = 0; rt < 2; ++rt)
#pragma unroll
        for (int reg = 0; reg < 4; ++reg) {
          int rg = tok0 + m0 + mw * 32 + rt * 16 + 4 * g + reg;
          int win = rg / 49, n = rg - win * 49;
          dst[((size_t)((win - win0) * 6 + hh) * 49 + n) * 32 + d] =
              f2b(S[rt][nt][reg] + bv);
        }
    }
    __syncthreads();  // stage(j+1) drained; cb reads done
  }
}

// ---------------- attention: one (window, head) per block (unchanged) ------
__global__ __launch_bounds__(256) void attn_kernel(
    const u16* __restrict__ qb, const u16* __restrict__ kb,
    const u16* __restrict__ vb, const float* __restrict__ rpb,
    const float* __restrict__ amask, u16* __restrict__ aout, int win0) {
  __shared__ __align__(16) u16 qs[64 * 32], ks[64 * 32], vst[32 * 64];
  __shared__ __align__(16) float S[64 * 68];
  __shared__ __align__(16) u16 P[64 * 64];
  int tid = threadIdx.x;
  int blk = blockIdx.x;
  int winl = blk / 6, head = blk - winl * 6;
  int wi = (win0 + winl) & 63;
  const size_t base = (size_t)(winl * 6 + head) * 49 * 32;
  {
    int row = tid >> 2, kcl = tid & 3;
    int phys = kcl ^ (row & 3);
    uint4 qv = make_uint4(0, 0, 0, 0), kv = qv, vv = qv;
    if (row < 49) {
      size_t o = base + (size_t)row * 32 + kcl * 8;
      qv = *(const uint4*)(qb + o);
      kv = *(const uint4*)(kb + o);
      vv = *(const uint4*)(vb + o);
    }
    *(uint4*)(qs + row * 32 + phys * 8) = qv;
    *(uint4*)(ks + row * 32 + phys * 8) = kv;
    alignas(16) u16 vu[8];
    *(uint4*)vu = vv;
    int c8 = kcl * 8;
    int kc = row >> 3;
#pragma unroll
    for (int j = 0; j < 8; ++j) {
      int d = c8 + j;
      vst[d * 64 + ((kc ^ (d & 7)) * 8) + (row & 7)] = vu[j];
    }
  }
  __syncthreads();
  int wave = tid >> 6, lane = tid & 63;
  int col = lane & 15, g = lane >> 4;
  {
    int ar = wave * 16 + col;
    bf16x8 af = *(const bf16x8*)(qs + ar * 32 + ((g ^ (ar & 3)) * 8));
    f32x4 zero = {0.f, 0.f, 0.f, 0.f};
#pragma unroll
    for (int nt = 0; nt < 4; ++nt) {
      int br = nt * 16 + col;
      bf16x8 bfr = *(const bf16x8*)(ks + br * 32 + ((g ^ (br & 3)) * 8));
      f32x4 sacc = MFMA16(af, bfr, zero);
#pragma unroll
      for (int reg = 0; reg < 4; ++reg)
        S[(wave * 16 + 4 * g + reg) * 68 + nt * 16 + col] = sacc[reg];
    }
  }
  __syncthreads();
  {
    int r = tid >> 2, p = tid & 3;
    int rb = (r < 49) ? r : 0;
    int i1 = rb / 7, j1 = rb - i1 * 7;
    const float scale = 0.17677669529663687f;
    const float* Srow = S + r * 68;
    float vals[16];
    float mx = -1e30f;
#pragma unroll
    for (int t = 0; t < 16; ++t) {
      int cc = p * 16 + t;
      float v = -1e30f;
      if (cc < 49) {
        int i2 = cc / 7, j2 = cc - i2 * 7;
        int ridx = (i1 - i2 + 6) * 13 + (j1 - j2 + 6);
        v = Srow[cc] * scale + rpb[ridx * 6 + head] +
            amask[(size_t)wi * 2401 + rb * 49 + cc];
      }
      vals[t] = v;
      mx = fmaxf(mx, v);
    }
    mx = fmaxf(mx, __shfl_xor(mx, 1, 64));
    mx = fmaxf(mx, __shfl_xor(mx, 2, 64));
    float se = 0.f;
#pragma unroll
    for (int t = 0; t < 16; ++t) {
      float e = __expf(vals[t] - mx);
      vals[t] = e;
      se += e;
    }
    se += __shfl_xor(se, 1, 64);
    se += __shfl_xor(se, 2, 64);
    float inv = 1.0f / se;
#pragma unroll
    for (int t = 0; t < 16; ++t) {
      int cc = p * 16 + t;
      P[r * 64 + (((cc >> 3) ^ (r & 7)) * 8) + (cc & 7)] = f2b(vals[t] * inv);
    }
  }
  __syncthreads();
  {
    f32x4 oacc[2] = {{0,0,0,0},{0,0,0,0}};
    int ar = wave * 16 + col;
#pragma unroll
    for (int kt = 0; kt < 2; ++kt) {
      bf16x8 pf = *(const bf16x8*)(P + ar * 64 + (((kt * 4 + g) ^ (ar & 7)) * 8));
#pragma unroll
      for (int nt = 0; nt < 2; ++nt) {
        int d = nt * 16 + col;
        bf16x8 vf = *(const bf16x8*)(vst + d * 64 + (((kt * 4 + g) ^ (d & 7)) * 8));
        oacc[nt] = MFMA16(pf, vf, oacc[nt]);
      }
    }
#pragma unroll
    for (int nt = 0; nt < 2; ++nt)
#pragma unroll
      for (int reg = 0; reg < 4; ++reg) {
        int rloc = wave * 16 + 4 * g + reg;
        if (rloc < 49)
          aout[((size_t)winl * 49 + rloc) * 192 + head * 32 + nt * 16 + col] =
              f2b(oacc[nt][reg]);
      }
  }
}

// ---------------- fused proj + window reverse + unshift + residual ---------
__global__ __launch_bounds__(256, 3) void proj_fused(
    const u16* __restrict__ aout, const u16* __restrict__ wf,
    const float* __restrict__ pb, const float* __restrict__ x,
    float* __restrict__ out, int tok0) {
  __shared__ __align__(16) u16 lds[24576];  // 48 KB
  u16* sA = lds;
  u16* b0 = lds;
  u16* b1 = lds + 12288;
  int tid = threadIdx.x, wave = tid >> 6, lane = tid & 63;
  int g = lane >> 4, c = lane & 15;
  int m0 = blockIdx.x * 64;
  stage_64x192(aout + (size_t)m0 * 192, 192, sA, wave, lane);
  asm volatile("s_waitcnt vmcnt(0)" ::: "memory");
  __syncthreads();
  int mw = wave >> 1, nw = wave & 1;
  bf16x8 afr[2][6];
#pragma unroll
  for (int rt = 0; rt < 2; ++rt) {
    int ar = mw * 32 + rt * 16 + c;
#pragma unroll
    for (int ks = 0; ks < 6; ++ks) {
      int ch = ks * 4 + g;
      int ph = (ch & 24) | ((ch ^ (ar & 7)) & 7);
      afr[rt][ks] = *(const bf16x8*)(sA + ar * 192 + ph * 8);
    }
  }
  size_t trow[2][4];
#pragma unroll
  for (int rt = 0; rt < 2; ++rt)
#pragma unroll
    for (int reg = 0; reg < 4; ++reg) {
      int rg = tok0 + m0 + mw * 32 + rt * 16 + 4 * g + reg;
      int win = rg / 49, n = rg - win * 49;
      int b_ = win >> 6, wi = win & 63;
      int wh = wi >> 3, ww = wi & 7;
      int rr = n / 7, cc = n - rr * 7;
      int hd_ = wh * 7 + rr + 3; if (hd_ >= 56) hd_ -= 56;
      int wd = ww * 7 + cc + 3; if (wd >= 56) wd -= 56;
      trow[rt][reg] = (size_t)b_ * 3136 + hd_ * 56 + wd;
    }
  __syncthreads();  // afr reads done -> sA region (b0) reusable
  stage_frags<24>(wf, b0, wave, lane);
  __syncthreads();  // b0 staged
  for (int j = 0; j < 3; ++j) {
    const u16* cb = (j & 1) ? b1 : b0;
    if (j < 2)
      stage_frags<24>(wf + (size_t)(j + 1) * 24 * 512, (j & 1) ? b0 : b1, wave,
                      lane);
    f32x4 S[2][2] = {{{0,0,0,0},{0,0,0,0}},{{0,0,0,0},{0,0,0,0}}};
#pragma unroll
    for (int nt = 0; nt < 2; ++nt)
#pragma unroll
      for (int ks = 0; ks < 6; ++ks) {
        bf16x8 bf = *(const bf16x8*)(cb + ((nw * 2 + nt) * 6 + ks) * 512 + lane * 8);
        S[0][nt] = MFMA16(afr[0][ks], bf, S[0][nt]);
        S[1][nt] = MFMA16(afr[1][ks], bf, S[1][nt]);
      }
#pragma unroll
    for (int nt = 0; nt < 2; ++nt) {
      int jc = j * 64 + nw * 32 + nt * 16 + c;
      float bv = pb[jc];
#pragma unroll
      for (int rt = 0; rt < 2; ++rt)
#pragma unroll
        for (int reg = 0; reg < 4; ++reg) {
          size_t o = trow[rt][reg] * 192 + jc;
          out[o] = x[o] + S[rt][nt][reg] + bv;
        }
    }
    __syncthreads();
  }
}

// ---------------- fused LN2 + fc1 + GELU + fc2 + residual ------------------
// Swapped-operand design: P stays in registers (lane-local pi-permuted k),
// one barrier per phase (weight dbuf), zero P-tile LDS traffic.
__global__ __launch_bounds__(256, 3) void mlp_fused(
    const float* __restrict__ n2w, const float* __restrict__ n2b,
    const u16* __restrict__ w1f, const float* __restrict__ b1,
    const u16* __restrict__ w2f, const float* __restrict__ b2,
    float* __restrict__ out) {
  __shared__ __align__(16) u16 lds[24576];  // 48 KB
  u16* c1a = lds;            // 12 frags (6144 u16) fc1 buf0
  u16* c1b = lds + 6144;
  u16* c2a = lds + 12288;    // fc2 buf0
  u16* c2b = lds + 18432;
  u16* sA  = lds;            // 64x192 overlay (c1a+c1b), dead after afr loads
  int tid = threadIdx.x, wave = tid >> 6, lane = tid & 63;
  int g = lane >> 4, c = lane & 15, wr = wave * 16;
  int m0 = blockIdx.x * 64;
  // --- LN2: wave owns 16 rows -> sA swizzled ---
  {
    float v[12][4];
    int rr[4];
#pragma unroll
    for (int reg = 0; reg < 4; ++reg) rr[reg] = m0 + wr + 4 * g + reg;
#pragma unroll
    for (int nt = 0; nt < 12; ++nt)
#pragma unroll
      for (int reg = 0; reg < 4; ++reg)
        v[nt][reg] = out[(size_t)rr[reg] * 192 + nt * 16 + c];
#pragma unroll
    for (int reg = 0; reg < 4; ++reg) {
      float s = 0.f;
#pragma unroll
      for (int nt = 0; nt < 12; ++nt) s += v[nt][reg];
      s += __shfl_xor(s, 1, 64); s += __shfl_xor(s, 2, 64);
      s += __shfl_xor(s, 4, 64); s += __shfl_xor(s, 8, 64);
      float m = s * (1.f / 192.f), q = 0.f;
#pragma unroll
      for (int nt = 0; nt < 12; ++nt) { float d = v[nt][reg] - m; q += d * d; }
      q += __shfl_xor(q, 1, 64); q += __shfl_xor(q, 2, 64);
      q += __shfl_xor(q, 4, 64); q += __shfl_xor(q, 8, 64);
      float rs = rsqrtf(q * (1.f / 192.f) + 1e-5f);
#pragma unroll
      for (int nt = 0; nt < 12; ++nt) v[nt][reg] = (v[nt][reg] - m) * rs;
    }
#pragma unroll
    for (int nt = 0; nt < 12; ++nt) {
      float wv = n2w[nt * 16 + c], bv = n2b[nt * 16 + c];
#pragma unroll
      for (int reg = 0; reg < 4; ++reg) {
        int r = wr + 4 * g + reg;
        int ch = nt * 2 + (c >> 3);
        int ph = (ch & 24) | ((ch ^ (r & 7)) & 7);
        sA[r * 192 + ph * 8 + (c & 7)] = f2b(v[nt][reg] * wv + bv);
      }
    }
  }
  __syncthreads();  // sA visible
  // A-frags for this wave's 16 m-rows (B-operand of swapped fc1)
  bf16x8 afr[6];
  {
    int ar = wr + c;
#pragma unroll
    for (int ks = 0; ks < 6; ++ks) {
      int ch = ks * 4 + g;
      int ph = (ch & 24) | ((ch ^ (ar & 7)) & 7);
      afr[ks] = *(const bf16x8*)(sA + ar * 192 + ph * 8);
    }
  }
  __syncthreads();  // all afr reads done -> sA region (c1a/c1b) reusable
  stage_frags<12>(w1f, c1a, wave, lane);
  stage_frags<12>(w2f, c2a, wave, lane);
  f32x4 o[12];
#pragma unroll
  for (int i = 0; i < 12; ++i) o[i] = (f32x4){0.f, 0.f, 0.f, 0.f};
  __syncthreads();  // prologue stage drained
  for (int j = 0; j < 24; ++j) {
    int cur = j & 1;
    const u16* r1 = cur ? c1b : c1a;
    const u16* r2 = cur ? c2b : c2a;
    if (j < 23) {
      stage_frags<12>(w1f + (size_t)(j + 1) * 6144, cur ? c1a : c1b, wave, lane);
      stage_frags<12>(w2f + (size_t)(j + 1) * 6144, cur ? c2a : c2b, wave, lane);
    }
    // ---- swapped fc1: S1[ht] = W1_frag x afr -> lane holds P^T[h][m=wr+c] ----
    f32x4 S1[2] = {{0,0,0,0},{0,0,0,0}};
#pragma unroll
    for (int ks = 0; ks < 6; ++ks) {
      bf16x8 w0 = *(const bf16x8*)(r1 + (0 * 6 + ks) * 512 + lane * 8);
      bf16x8 w1v = *(const bf16x8*)(r1 + (1 * 6 + ks) * 512 + lane * 8);
      S1[0] = MFMA16(w0, afr[ks], S1[0]);
      S1[1] = MFMA16(w1v, afr[ks], S1[1]);
    }
    // ---- GELU + lane-local bf16 pack: pf slot (g,i) = h pi(g,i) ----
    union { u16 h[8]; bf16x8 v; } pu;
    float4 bv0 = *(const float4*)(b1 + j * 32 + 4 * g);
    float4 bv1 = *(const float4*)(b1 + j * 32 + 16 + 4 * g);
#pragma unroll
    for (int r = 0; r < 4; ++r) {
      float v0 = S1[0][r] + ((const float*)&bv0)[r];
      float u20 = v0 * (1.5957691216f + 0.0713548163f * v0 * v0);
      pu.h[r] = f2b(v0 / (1.f + __expf(-u20)));
      float v1 = S1[1][r] + ((const float*)&bv1)[r];
      float u21 = v1 * (1.5957691216f + 0.0713548163f * v1 * v1);
      pu.h[r + 4] = f2b(v1 / (1.f + __expf(-u21)));
    }
    // ---- swapped PV: o[ct] += W2_frag(pi-packed) x pf ----
#pragma unroll
    for (int ct = 0; ct < 12; ++ct) {
      bf16x8 wf2 = *(const bf16x8*)(r2 + ct * 512 + lane * 8);
      o[ct] = MFMA16(wf2, pu.v, o[ct]);
    }
    __syncthreads();  // r1/r2 reads done; stage(j+1) drained
  }
  // epilogue: lane holds O^T[cout=ct*16+4g+reg][m=wr+c]; residual RMW + bias
  size_t rowoff = (size_t)(m0 + wr + c) * 192;
#pragma unroll
  for (int ct = 0; ct < 12; ++ct) {
    float4 b4 = *(const float4*)(b2 + ct * 16 + 4 * g);
#pragma unroll
    for (int r = 0; r < 4; ++r) {
      size_t oo = rowoff + ct * 16 + 4 * g + r;
      out[oo] = out[oo] + o[ct][r] + ((const float*)&b4)[r];
    }
  }
}

extern "C" void kernel_launch(void* const* d_in, const int* in_sizes, int n_in,
                              void* d_out, int out_size, void* d_ws, size_t ws_size,
                              hipStream_t stream) {
  (void)in_sizes; (void)n_in; (void)out_size;
  const float* x     = (const float*)d_in[0];
  const float* amask = (const float*)d_in[1];
  const float* n1w   = (const float*)d_in[2];
  const float* n1b   = (const float*)d_in[3];
  const float* qkvw  = (const float*)d_in[4];
  const float* qkvb  = (const float*)d_in[5];
  const float* rpb   = (const float*)d_in[6];
  const float* projw = (const float*)d_in[7];
  const float* projb = (const float*)d_in[8];
  const float* n2w   = (const float*)d_in[9];
  const float* n2b   = (const float*)d_in[10];
  const float* fc1w  = (const float*)d_in[11];
  const float* fc1b  = (const float*)d_in[12];
  const float* fc2w  = (const float*)d_in[13];
  const float* fc2b  = (const float*)d_in[14];
  float* out = (float*)d_out;
  char* ws = (char*)d_ws;

  u16* qkvwf = (u16*)(ws);                               // ct-major 36x6
  u16* projwf = (u16*)(ws + 221184);                     // ct-major 12x6
  u16* fc1wf = (u16*)(ws + 221184 + 73728);              // ct-major 48x6
  u16* fc2wf = (u16*)(ws + 221184 + 73728 + 294912);     // pi-packed hs-major 24x12
  char* arena = ws + (1 << 20);
  size_t arena_sz = ws_size > (1 << 20) ? ws_size - (1 << 20) : 0;

  pack_kernel<<<(36 * 6 * 64 + 255) / 256, 256, 0, stream>>>(qkvw, qkvwf, 36, 6, 192, 0);
  pack_kernel<<<(12 * 6 * 64 + 255) / 256, 256, 0, stream>>>(projw, projwf, 12, 6, 192, 0);
  pack_kernel<<<(48 * 6 * 64 + 255) / 256, 256, 0, stream>>>(fc1w, fc1wf, 48, 6, 192, 0);
  pack2_kernel<<<(24 * 12 * 64 + 255) / 256, 256, 0, stream>>>(fc2w, fc2wf);

  // ---- attention path, chunked over window groups (ws-size adaptive) ----
  int NCA = 1;
  while (NCA < 16 && 4ull * (size_t)(2048 / NCA) * 49 * 192 * 2 > arena_sz)
    NCA <<= 1;
  int Wc = 2048 / NCA;
  size_t Sx = (size_t)Wc * 49 * 192;  // u16 elements per buffer
  for (int cch = 0; cch < NCA; ++cch) {
    int win0 = cch * Wc;
    int tok0 = win0 * 49;
    u16* aout_c = (u16*)arena;
    u16* qb = (u16*)arena + Sx;
    u16* kb = qb + Sx;
    u16* vb = kb + Sx;
    int rows = Wc * 49;
    qkv_fused<<<rows / 64, 256, 0, stream>>>(x, n1w, n1b, qkvwf, qkvb,
                                             qb, kb, vb, tok0);
    attn_kernel<<<Wc * 6, 256, 0, stream>>>(qb, kb, vb, rpb, amask, aout_c,
                                            win0);
    proj_fused<<<rows / 64, 256, 0, stream>>>(aout_c, projwf, projb, x, out,
                                              tok0);
  }

  // ---- fused MLP: swapped operands, register-resident P, 1 barrier/phase ----
  mlp_fused<<<1568, 256, 0, stream>>>(n2w, n2b, fc1wf, fc1b, fc2wf, fc2b,
                                      out);
}